// Round 2
// baseline (397.111 us; speedup 1.0000x reference)
//
#include <hip/hip_runtime.h>

#define HEADS 6
#define HD 16
#define NTOK 512
#define PD 6
#define NTAB 43
#define TABSTRIDE 64

__device__ __forceinline__ int sigma(int t) {
    return (t >> 6) + ((t >> 3) & 7) + (t & 7);
}

// -------- tiny pos-MLP: 2 branches x 43 rows x 6 heads --------
__device__ void ln_relu_lin(const float* x, const float* g, const float* b,
                            const float* W, const float* bb, float* y) {
    float mu = 0.f;
#pragma unroll
    for (int k = 0; k < PD; ++k) mu += x[k];
    mu *= (1.f / PD);
    float var = 0.f;
#pragma unroll
    for (int k = 0; k < PD; ++k) { float d = x[k] - mu; var += d * d; }
    var *= (1.f / PD);
    float r = rsqrtf(var + 1e-5f);
    float t[PD];
#pragma unroll
    for (int k = 0; k < PD; ++k) {
        float v = (x[k] - mu) * r * g[k] + b[k];
        t[k] = fmaxf(v, 0.f);
    }
#pragma unroll
    for (int p = 0; p < PD; ++p) {
        float s = bb[p];
#pragma unroll
        for (int k = 0; k < PD; ++k) s = fmaf(t[k], W[p * PD + k], s);
        y[p] = s;
    }
}

__global__ void pos_mlp_kernel(
    const float* __restrict__ w0, const float* __restrict__ b0,
    const float* __restrict__ g1, const float* __restrict__ be1,
    const float* __restrict__ w1, const float* __restrict__ bb1,
    const float* __restrict__ g2, const float* __restrict__ be2,
    const float* __restrict__ w2, const float* __restrict__ bb2,
    const float* __restrict__ g3, const float* __restrict__ be3,
    const float* __restrict__ w3, const float* __restrict__ bb3,
    float* __restrict__ tab)
{
    int t = threadIdx.x;
    if (t >= 2 * NTAB) return;
    int br = t / NTAB;
    int j = t - br * NTAB;
    // biases-table row j (j < 43 < 225): (bh,bw,bd) = (-7, j/15 - 7, j%15 - 7)
    float bx = -7.f, by = -7.f + (float)(j / 15), bz = -7.f + (float)(j % 15);
    float x[PD], y[PD];
    const float* W = w0 + br * (PD * 3);
#pragma unroll
    for (int p = 0; p < PD; ++p)
        x[p] = bx * W[p * 3 + 0] + by * W[p * 3 + 1] +
               bz * W[p * 3 + 2] + b0[br * PD + p];
    ln_relu_lin(x, g1 + br * PD, be1 + br * PD, w1 + br * PD * PD, bb1 + br * PD, y);
    ln_relu_lin(y, g2 + br * PD, be2 + br * PD, w2 + br * PD * PD, bb2 + br * PD, x);
    ln_relu_lin(x, g3 + br * PD, be3 + br * PD, w3 + br * HEADS * PD, bb3 + br * HEADS, y);
#pragma unroll
    for (int hh = 0; hh < HEADS; ++hh)
        tab[(br * HEADS + hh) * TABSTRIDE + j] = y[hh];
}

// -------- pass 1: x = softmax(g*s @ k^T + rpb0) @ v  (fp32 out to ws) --------
// grid: 576 blocks = (b,h) pair * 2 row-halves; 256 threads, 1 query row each
__global__ __launch_bounds__(256) void attn_pass1_kernel(
    const float* __restrict__ qkv, const float* __restrict__ grd,
    const float* __restrict__ tab, float* __restrict__ xout)
{
    __shared__ float sK[NTOK * HD];
    __shared__ float sV[NTOK * HD];
    const int pair = blockIdx.x >> 1;
    const int half = blockIdx.x & 1;
    const int b = pair / HEADS, h = pair - (pair / HEADS) * HEADS;
    const int tid = threadIdx.x;

    const size_t base = (size_t)b * NTOK * 288;
    const float* kb = qkv + base + 96 + h * HD;
    const float* vb = qkv + base + 192 + h * HD;
    for (int c = tid; c < NTOK * HD / 4; c += 256) {
        int j = c >> 2, c4 = (c & 3) << 2;
        *(float4*)&sK[j * HD + c4] = *(const float4*)(kb + j * 288 + c4);
        *(float4*)&sV[j * HD + c4] = *(const float4*)(vb + j * 288 + c4);
    }

    const int i0 = half * 256 + tid;
    float q0[HD];
    const float* gb = grd + (size_t)b * NTOK * 96 + h * HD + (size_t)i0 * 96;
#pragma unroll
    for (int cc = 0; cc < 4; ++cc) {
        float4 ua = *(const float4*)(gb + cc * 4);
        q0[cc * 4 + 0] = ua.x * 0.25f;
        q0[cc * 4 + 1] = ua.y * 0.25f;
        q0[cc * 4 + 2] = ua.z * 0.25f;
        q0[cc * 4 + 3] = ua.w * 0.25f;
    }
    __syncthreads();

    const float* tabh = tab + h * TABSTRIDE;  // branch 0
    const int s0 = sigma(i0) + 21;
    float acc[HD];
#pragma unroll
    for (int c = 0; c < HD; ++c) acc[c] = 0.f;
    float l0 = 0.f;

    for (int j = 0; j < NTOK; ++j) {
        const float* kr = sK + j * HD;
        float d0 = 0.f;
#pragma unroll
        for (int c = 0; c < HD; ++c) d0 = fmaf(q0[c], kr[c], d0);
        int sj = sigma(j);
        float p0 = __expf(d0 + tabh[s0 - sj]);
        l0 += p0;
        const float* vr = sV + j * HD;
#pragma unroll
        for (int c = 0; c < HD; ++c) acc[c] = fmaf(p0, vr[c], acc[c]);
    }
    float r0 = 1.0f / l0;
    float* xo = xout + (size_t)pair * NTOK * HD + (size_t)i0 * HD;
#pragma unroll
    for (int c = 0; c < HD; c += 4)
        *(float4*)&xo[c] = make_float4(acc[c] * r0, acc[c + 1] * r0, acc[c + 2] * r0, acc[c + 3] * r0);
}

// -------- pass 2: out = softmax(q*s @ g^T + rpb1) @ x  (fp32 out) --------
__global__ __launch_bounds__(256) void attn_pass2_kernel(
    const float* __restrict__ qkv, const float* __restrict__ grd,
    const float* __restrict__ tab, const float* __restrict__ xin,
    float* __restrict__ out)
{
    __shared__ float sK[NTOK * HD];
    __shared__ float sV[NTOK * HD];
    const int pair = blockIdx.x >> 1;
    const int half = blockIdx.x & 1;
    const int b = pair / HEADS, h = pair - (pair / HEADS) * HEADS;
    const int tid = threadIdx.x;

    const float* kb = grd + (size_t)b * NTOK * 96 + h * HD;   // keys = grid
    const float* vb = xin + (size_t)pair * NTOK * HD;         // values = pass1 out
    for (int c = tid; c < NTOK * HD / 4; c += 256) {
        int j = c >> 2, c4 = (c & 3) << 2;
        *(float4*)&sK[j * HD + c4] = *(const float4*)(kb + j * 96 + c4);
        *(float4*)&sV[c * 4] = *(const float4*)(vb + c * 4);
    }

    const int i0 = half * 256 + tid;
    float q0[HD];
    const float* qb = qkv + (size_t)b * NTOK * 288 + h * HD + (size_t)i0 * 288;  // q slice
#pragma unroll
    for (int cc = 0; cc < 4; ++cc) {
        float4 ua = *(const float4*)(qb + cc * 4);
        q0[cc * 4 + 0] = ua.x * 0.25f;
        q0[cc * 4 + 1] = ua.y * 0.25f;
        q0[cc * 4 + 2] = ua.z * 0.25f;
        q0[cc * 4 + 3] = ua.w * 0.25f;
    }
    __syncthreads();

    const float* tabh = tab + (HEADS + h) * TABSTRIDE;  // branch 1
    const int s0 = sigma(i0) + 21;
    float acc[HD];
#pragma unroll
    for (int c = 0; c < HD; ++c) acc[c] = 0.f;
    float l0 = 0.f;

    for (int j = 0; j < NTOK; ++j) {
        const float* kr = sK + j * HD;
        float d0 = 0.f;
#pragma unroll
        for (int c = 0; c < HD; ++c) d0 = fmaf(q0[c], kr[c], d0);
        int sj = sigma(j);
        float p0 = __expf(d0 + tabh[s0 - sj]);
        l0 += p0;
        const float* vr = sV + j * HD;
#pragma unroll
        for (int c = 0; c < HD; ++c) acc[c] = fmaf(p0, vr[c], acc[c]);
    }
    float r0 = 1.0f / l0;

    float* ob = out + (size_t)b * NTOK * 96 + (size_t)i0 * 96 + h * HD;
#pragma unroll
    for (int c = 0; c < HD; c += 4)
        *(float4*)&ob[c] = make_float4(acc[c] * r0, acc[c + 1] * r0, acc[c + 2] * r0, acc[c + 3] * r0);
}

extern "C" void kernel_launch(void* const* d_in, const int* in_sizes, int n_in,
                              void* d_out, int out_size, void* d_ws, size_t ws_size,
                              hipStream_t stream)
{
    const float* qkv = (const float*)d_in[0];
    const float* grd = (const float*)d_in[1];
    float* tab = (float*)d_ws;              // 2*6*64 floats = 3 KB
    float* x   = (float*)d_ws + 1024;       // 288*512*16 floats = 9.4 MB

    pos_mlp_kernel<<<1, 128, 0, stream>>>(
        (const float*)d_in[2], (const float*)d_in[3],
        (const float*)d_in[4], (const float*)d_in[5],
        (const float*)d_in[6], (const float*)d_in[7],
        (const float*)d_in[8], (const float*)d_in[9],
        (const float*)d_in[10], (const float*)d_in[11],
        (const float*)d_in[12], (const float*)d_in[13],
        (const float*)d_in[14], (const float*)d_in[15],
        tab);

    attn_pass1_kernel<<<48 * HEADS * 2, 256, 0, stream>>>(qkv, grd, tab, x);
    attn_pass2_kernel<<<48 * HEADS * 2, 256, 0, stream>>>(qkv, grd, tab, x, (float*)d_out);
}

// Round 3
// 307.479 us; speedup vs baseline: 1.2915x; 1.2915x over previous
//
#include <hip/hip_runtime.h>

#define HEADS 6
#define HD 16
#define NTOK 512
#define PD 6
#define TABSTRIDE 64

__device__ __forceinline__ int sigma(int t) {
    return (t >> 6) + ((t >> 3) & 7) + (t & 7);
}

// -------- tiny pos-MLP: 2 branches x 43 rows x 6 heads --------
__device__ void ln_relu_lin(const float* x, const float* g, const float* b,
                            const float* W, const float* bb, float* y) {
    float mu = 0.f;
#pragma unroll
    for (int k = 0; k < PD; ++k) mu += x[k];
    mu *= (1.f / PD);
    float var = 0.f;
#pragma unroll
    for (int k = 0; k < PD; ++k) { float d = x[k] - mu; var += d * d; }
    var *= (1.f / PD);
    float r = rsqrtf(var + 1e-5f);
    float t[PD];
#pragma unroll
    for (int k = 0; k < PD; ++k) {
        float v = (x[k] - mu) * r * g[k] + b[k];
        t[k] = fmaxf(v, 0.f);
    }
#pragma unroll
    for (int p = 0; p < PD; ++p) {
        float s = bb[p];
#pragma unroll
        for (int k = 0; k < PD; ++k) s = fmaf(t[k], W[p * PD + k], s);
        y[p] = s;
    }
}

__global__ void pos_mlp_kernel(
    const float* __restrict__ w0, const float* __restrict__ b0,
    const float* __restrict__ g1, const float* __restrict__ be1,
    const float* __restrict__ w1, const float* __restrict__ bb1,
    const float* __restrict__ g2, const float* __restrict__ be2,
    const float* __restrict__ w2, const float* __restrict__ bb2,
    const float* __restrict__ g3, const float* __restrict__ be3,
    const float* __restrict__ w3, const float* __restrict__ bb3,
    float* __restrict__ tab)
{
    int t = threadIdx.x;
    if (t >= 2 * 43) return;
    int br = t / 43;
    int j = t - br * 43;
    // biases-table row j (j < 43 < 225): (bh,bw,bd) = (-7, j/15 - 7, j%15 - 7)
    float bx = -7.f, by = -7.f + (float)(j / 15), bz = -7.f + (float)(j % 15);
    float x[PD], y[PD];
    const float* W = w0 + br * (PD * 3);
#pragma unroll
    for (int p = 0; p < PD; ++p)
        x[p] = bx * W[p * 3 + 0] + by * W[p * 3 + 1] +
               bz * W[p * 3 + 2] + b0[br * PD + p];
    ln_relu_lin(x, g1 + br * PD, be1 + br * PD, w1 + br * PD * PD, bb1 + br * PD, y);
    ln_relu_lin(y, g2 + br * PD, be2 + br * PD, w2 + br * PD * PD, bb2 + br * PD, x);
    ln_relu_lin(x, g3 + br * PD, be3 + br * PD, w3 + br * HEADS * PD, bb3 + br * HEADS, y);
#pragma unroll
    for (int hh = 0; hh < HEADS; ++hh)
        tab[(br * HEADS + hh) * TABSTRIDE + j] = y[hh];
}

// -------- unified attention pass --------
// pass 0: x   = softmax(0.25*g @ k^T + rpb0) @ v   (fp32 to xbuf)
// pass 1: out = softmax(0.25*q @ g^T + rpb1) @ x
// grid: 288 pairs * 4 row-groups = 1152 blocks; 256 threads.
// tid = (jslice<<7) | row_local : 128 rows/block, j split in 2 halves of 256.
// K/V tiled through LDS in 4 steps of 64 j per slice (16.5 KiB LDS).
__global__ __launch_bounds__(256, 4) void attn_kernel(
    int pass,
    const float* __restrict__ qkv, const float* __restrict__ grd,
    const float* __restrict__ tab, float* __restrict__ xbuf,
    float* __restrict__ outp)
{
    __shared__ float smem[4096];   // K: [0,2048) = [slice][jj][16]; V: [2048,4096)
    __shared__ float stab[64];

    const int pair = blockIdx.x >> 2;
    const int grp  = blockIdx.x & 3;
    const int b = pair / HEADS, h = pair - (pair / HEADS) * HEADS;
    const int tid = threadIdx.x;
    const int rl = tid & 127;       // row_local
    const int js = tid >> 7;        // j-slice 0/1 (wave-uniform)

    const float *qb, *kb, *vb, *tb;
    float* ob;
    int qs, ks, vs, os;
    if (pass == 0) {
        qb = grd + (size_t)b * NTOK * 96 + h * HD;        qs = 96;
        kb = qkv + (size_t)b * NTOK * 288 + 96 + h * HD;  ks = 288;
        vb = kb + 96;                                     vs = 288;
        ob = xbuf + (size_t)pair * NTOK * HD;             os = HD;
        tb = tab + h * TABSTRIDE;
    } else {
        qb = qkv + (size_t)b * NTOK * 288 + h * HD;       qs = 288;
        kb = grd + (size_t)b * NTOK * 96 + h * HD;        ks = 96;
        vb = xbuf + (size_t)pair * NTOK * HD;             vs = HD;
        ob = outp + (size_t)b * NTOK * 96 + h * HD;       os = 96;
        tb = tab + (HEADS + h) * TABSTRIDE;
    }
    if (tid < 64) stab[tid] = tb[tid];

    const int i0 = grp * 128 + rl;
    float q0[HD];
    {
        const float* qr = qb + (size_t)i0 * qs;
#pragma unroll
        for (int cc = 0; cc < 4; ++cc) {
            float4 u = *(const float4*)(qr + cc * 4);
            q0[4 * cc + 0] = u.x * 0.25f; q0[4 * cc + 1] = u.y * 0.25f;
            q0[4 * cc + 2] = u.z * 0.25f; q0[4 * cc + 3] = u.w * 0.25f;
        }
    }
    const int s0 = sigma(i0) + 21;

    float acc[HD];
#pragma unroll
    for (int c = 0; c < HD; ++c) acc[c] = 0.f;
    float l0 = 0.f;

    for (int t = 0; t < 4; ++t) {
        __syncthreads();   // previous tile fully consumed (and stab ready at t=0)
        // stage 128 K rows + 128 V rows: slice s uses global j = s*256 + t*64 + jj
#pragma unroll
        for (int k = 0; k < 4; ++k) {
            int cc = tid + k * 256;          // [0,1024) float4 chunks
            int isV = cc >> 9;
            int r = (cc >> 2) & 127;         // staged row: slice = r>>6, jj = r&63
            int c4 = (cc & 3) << 2;
            int jg = (r >> 6) * 256 + t * 64 + (r & 63);
            const float* src = (isV ? vb + (size_t)jg * vs : kb + (size_t)jg * ks) + c4;
            *(float4*)&smem[isV * 2048 + r * HD + c4] = *(const float4*)src;
        }
        __syncthreads();

        const float* kr = smem + js * 1024;
        const float* vr = smem + 2048 + js * 1024;
        const int jg0 = js * 256 + t * 64;
        for (int j8 = 0; j8 < 64; j8 += 8) {
            const int sjb = sigma(jg0 + j8);   // wave-uniform
            const int tix = s0 - sjb;          // per-lane
#pragma unroll
            for (int l = 0; l < 8; ++l) {
                const float* krow = kr + (j8 + l) * HD;
                float d0 = 0.f;
#pragma unroll
                for (int c = 0; c < HD; ++c) d0 = fmaf(q0[c], krow[c], d0);
                float p = __expf(d0 + stab[tix - l]);
                l0 += p;
                const float* vrow = vr + (j8 + l) * HD;
#pragma unroll
                for (int c = 0; c < HD; ++c) acc[c] = fmaf(p, vrow[c], acc[c]);
            }
        }
    }

    // combine the two j-slices, then normalize + store (slice-0 threads)
    __syncthreads();
    float* compb = smem + rl * 20;
    if (js) {
#pragma unroll
        for (int c = 0; c < HD; c += 4)
            *(float4*)&compb[c] = make_float4(acc[c], acc[c + 1], acc[c + 2], acc[c + 3]);
        compb[16] = l0;
    }
    __syncthreads();
    if (!js) {
#pragma unroll
        for (int c = 0; c < HD; ++c) acc[c] += compb[c];
        l0 += compb[16];
        float r0 = 1.f / l0;
        float* o = ob + (size_t)i0 * os;
#pragma unroll
        for (int c = 0; c < HD; c += 4)
            *(float4*)&o[c] = make_float4(acc[c] * r0, acc[c + 1] * r0,
                                          acc[c + 2] * r0, acc[c + 3] * r0);
    }
}

extern "C" void kernel_launch(void* const* d_in, const int* in_sizes, int n_in,
                              void* d_out, int out_size, void* d_ws, size_t ws_size,
                              hipStream_t stream)
{
    const float* qkv = (const float*)d_in[0];
    const float* grd = (const float*)d_in[1];
    float* tab = (float*)d_ws;              // 2*6*64 floats = 3 KB
    float* x   = (float*)d_ws + 1024;       // 288*512*16 floats = 9.4 MB

    pos_mlp_kernel<<<1, 128, 0, stream>>>(
        (const float*)d_in[2], (const float*)d_in[3],
        (const float*)d_in[4], (const float*)d_in[5],
        (const float*)d_in[6], (const float*)d_in[7],
        (const float*)d_in[8], (const float*)d_in[9],
        (const float*)d_in[10], (const float*)d_in[11],
        (const float*)d_in[12], (const float*)d_in[13],
        (const float*)d_in[14], (const float*)d_in[15],
        tab);

    attn_kernel<<<1152, 256, 0, stream>>>(0, qkv, grd, tab, x, nullptr);
    attn_kernel<<<1152, 256, 0, stream>>>(1, qkv, grd, tab, x, (float*)d_out);
}